// Round 1
// baseline (319.669 us; speedup 1.0000x reference)
//
#include <hip/hip_runtime.h>

// Tiny pre-kernel: filter sums -> ws[0..3] = {sum(gl), sum(gh), sum(fl), sum(fh)}
__global__ void qwt_sums_kernel(const float* __restrict__ gl, const float* __restrict__ gh,
                                const float* __restrict__ fl, const float* __restrict__ fh,
                                float* __restrict__ ws) {
    int t = threadIdx.x;
    if (t < 4) {
        const float* p = (t == 0) ? gl : (t == 1) ? gh : (t == 2) ? fl : fh;
        float s = 0.f;
        #pragma unroll
        for (int i = 0; i < 16; i++) s += p[i];
        ws[t] = s;
    }
}

// One wave (64 lanes) == one output row (256 px, 4 px/lane).
// grid: 4096 blocks x 256 threads = 16384 waves = 4*16*256 rows.
__global__ __launch_bounds__(256) void qwt_main_kernel(const float* __restrict__ img,
                                                       const float* __restrict__ ws,
                                                       float* __restrict__ out) {
    const float w0 = -0.09375f, w1 = 0.59375f;  // CUBIC_W = {w0, w1, w1, w0}

    int t    = blockIdx.x * 256 + threadIdx.x;
    int lane = t & 63;
    int row  = t >> 6;        // 0..16383 flat (b,c,y)
    int y    = row & 255;
    int bc   = row >> 8;      // 0..63 = b*16 + c
    int x0   = lane << 2;     // 4 output px per lane

    // load scales early (uniform, L1-broadcast)
    float sg = ws[0], sh = ws[1], sfl = ws[2], sfh = ws[3];

    const float* src = img + (size_t)bc * (512 * 512);

    // clamped source columns for outputs x0..x0+3: cols 2*x0-1 .. 2*x0+8
    int cb = 2 * x0 - 1;
    int c[10];
    #pragma unroll
    for (int k = 0; k < 10; k++) {
        int cc = cb + k;
        cc = cc < 0 ? 0 : (cc > 511 ? 511 : cc);
        c[k] = cc;
    }

    float acc0 = 0.f, acc1 = 0.f, acc2 = 0.f, acc3 = 0.f;
    #pragma unroll
    for (int j = 0; j < 4; j++) {
        int ry = 2 * y - 1 + j;               // wave-uniform
        ry = ry < 0 ? 0 : (ry > 511 ? 511 : ry);
        const float* rp = src + (size_t)ry * 512;
        float r0 = rp[c[0]], r1 = rp[c[1]], r2 = rp[c[2]], r3 = rp[c[3]], r4 = rp[c[4]];
        float r5 = rp[c[5]], r6 = rp[c[6]], r7 = rp[c[7]], r8 = rp[c[8]], r9 = rp[c[9]];
        float wj = (j == 0 || j == 3) ? w0 : w1;
        float h0 = w0 * r0 + w1 * r1 + w1 * r2 + w0 * r3;
        float h1 = w0 * r2 + w1 * r3 + w1 * r4 + w0 * r5;
        float h2 = w0 * r4 + w1 * r5 + w1 * r6 + w0 * r7;
        float h3 = w0 * r6 + w1 * r7 + w1 * r8 + w0 * r9;
        acc0 += wj * h0; acc1 += wj * h1; acc2 += wj * h2; acc3 += wj * h3;
    }

    int b  = bc >> 4;          // batch 0..3
    int cc_ = bc & 15;         // channel 0..15
    size_t rowoff = ((size_t)y << 8) + (size_t)x0;   // y*256 + x0
    const size_t P  = 65536;                         // 256*256
    const size_t HB = 16777216;                      // LL element count

    // factor tables: q&1 selects {sg|sfl} / {sh|sfh} for the first filter,
    // q&2 selects the second.
    #pragma unroll
    for (int q = 0; q < 4; q++) {
        float f1g = (q & 1) ? sfl : sg;
        float f1h = (q & 1) ? sfh : sh;
        float f2g = (q & 2) ? sfl : sg;
        float f2h = (q & 2) ? sfh : sh;

        size_t chan = (size_t)(b * 64 + q * 16 + cc_);

        // LL: scale f1g*f2g
        {
            float s = f1g * f2g;
            float4 v = make_float4(acc0 * s, acc1 * s, acc2 * s, acc3 * s);
            *(float4*)(out + chan * P + rowoff) = v;
        }
        // H: r=0 (f1g*f2h), r=1 (f1h*f2g), r=2 (f1h*f2h)
        size_t hbase = HB + chan * 3 * P + rowoff;
        {
            float s = f1g * f2h;
            float4 v = make_float4(acc0 * s, acc1 * s, acc2 * s, acc3 * s);
            *(float4*)(out + hbase) = v;
        }
        {
            float s = f1h * f2g;
            float4 v = make_float4(acc0 * s, acc1 * s, acc2 * s, acc3 * s);
            *(float4*)(out + hbase + P) = v;
        }
        {
            float s = f1h * f2h;
            float4 v = make_float4(acc0 * s, acc1 * s, acc2 * s, acc3 * s);
            *(float4*)(out + hbase + 2 * P) = v;
        }
    }
}

extern "C" void kernel_launch(void* const* d_in, const int* in_sizes, int n_in,
                              void* d_out, int out_size, void* d_ws, size_t ws_size,
                              hipStream_t stream) {
    const float* img = (const float*)d_in[0];
    const float* gl  = (const float*)d_in[1];
    const float* gh  = (const float*)d_in[2];
    const float* fl  = (const float*)d_in[3];
    const float* fh  = (const float*)d_in[4];
    float* out = (float*)d_out;
    float* ws  = (float*)d_ws;

    qwt_sums_kernel<<<1, 64, 0, stream>>>(gl, gh, fl, fh, ws);
    // 4*16*256 rows, one wave per row, 4 waves per block
    qwt_main_kernel<<<4096, 256, 0, stream>>>(img, ws, out);
}